// Round 1
// baseline (2351.162 us; speedup 1.0000x reference)
//
#include <hip/hip_runtime.h>
#include <hip/hip_fp16.h>

#define B_ 256
#define S_ 512
#define D_ 200
#define H_ 256

typedef _Float16 half2_t __attribute__((ext_vector_type(2)));
typedef _Float16 half8_t __attribute__((ext_vector_type(8)));
typedef float    floatx4 __attribute__((ext_vector_type(4)));

__device__ __forceinline__ float fdot2f(half2_t a, half2_t b, float c) {
#if __has_builtin(__builtin_amdgcn_fdot2)
    return __builtin_amdgcn_fdot2(a, b, c, false);
#else
    return c + (float)a[0] * (float)b[0] + (float)a[1] * (float)b[1];
#endif
}

__device__ __forceinline__ half2_t bc_h2(unsigned int u) {
    return __builtin_bit_cast(half2_t, u);
}

__device__ __forceinline__ float fast_sig(float x) {
    return 1.f / (1.f + __expf(-x));
}
__device__ __forceinline__ float fast_tanh(float x) {
    x = fminf(15.f, fmaxf(-15.f, x));
    float e = __expf(2.f * x);
    return (e - 1.f) / (e + 1.f);
}

// ---------------------------------------------------------------------------
// prep: build fp16 weight layouts in workspace.
//   W4T [1024][224]: W4T[n][k] = Wg[k][j] (x-part rows 0..199, zero-padded to 224)
//   WhT [1024][256]: WhT[n][k] = Wg[200+k][j] (h-part), n = g*256+j
// ---------------------------------------------------------------------------
__global__ void prep(const float* __restrict__ Wi, const float* __restrict__ Wf,
                     const float* __restrict__ Wo, const float* __restrict__ Wz,
                     _Float16* __restrict__ W4T, _Float16* __restrict__ WhT) {
    const int n = blockIdx.x;      // 0..1023
    const int t = threadIdx.x;     // 0..255
    const int g = n >> 8, j = n & 255;
    const float* Wg = (g == 0) ? Wi : (g == 1) ? Wf : (g == 2) ? Wo : Wz;
    if (t < 224)
        W4T[(size_t)n * 224 + t] = (t < D_) ? (_Float16)Wg[t * 256 + j] : (_Float16)0.f;
    WhT[(size_t)n * 256 + t] = (_Float16)Wg[(D_ + t) * 256 + j];
}

// ---------------------------------------------------------------------------
// gemm_x: G[m][n] = sum_k X[m][k] * W4T[n][k],  m in [0,131072), n in [0,1024)
// fp16 MFMA 16x16x32, 128x128 tile, K padded to 224 (pad rows of W4T are zero,
// so over-read garbage in A contributes 0).
// ---------------------------------------------------------------------------
__global__ __launch_bounds__(256) void gemm_x(const float* __restrict__ X,
                                              const _Float16* __restrict__ W4T,
                                              _Float16* __restrict__ G) {
    __shared__ __align__(16) _Float16 As[128][40];  // +8 pad halfs to break bank strides
    __shared__ __align__(16) _Float16 Bs[128][40];

    const int mt = blockIdx.x >> 3;
    const int nt = blockIdx.x & 7;
    const int m0 = mt * 128, n0 = nt * 128;
    const int tid  = threadIdx.x;
    const int lane = tid & 63, wave = tid >> 6;
    const int quad = lane >> 4, l16 = lane & 15;
    const int mq = (wave & 1) * 64, nq = (wave >> 1) * 64;

    floatx4 acc[4][4];
#pragma unroll
    for (int i = 0; i < 4; ++i)
#pragma unroll
        for (int j = 0; j < 4; ++j) acc[i][j] = (floatx4){0.f, 0.f, 0.f, 0.f};

    const int srow = tid >> 1;            // 0..127
    const int koff = (tid & 1) * 16;      // 0 or 16

    for (int kt = 0; kt < 7; ++kt) {
        const int k0 = kt * 32;
        // ---- stage A tile: X fp32 -> fp16 LDS ----
        {
            const int m = m0 + srow;
            const float* xr = X + (size_t)m * D_ + (k0 + koff);
            half8_t v0, v1;
            if (m < B_ * S_ - 1) {
                // may over-read past k=199 into the next row: valid memory,
                // finite values, multiplied by zero weight rows.
                const floatx4* xp = (const floatx4*)xr;
                floatx4 f0 = xp[0], f1 = xp[1], f2 = xp[2], f3 = xp[3];
#pragma unroll
                for (int i = 0; i < 4; ++i) {
                    v0[i]     = (_Float16)f0[i];
                    v0[4 + i] = (_Float16)f1[i];
                    v1[i]     = (_Float16)f2[i];
                    v1[4 + i] = (_Float16)f3[i];
                }
            } else {  // very last row: no over-read past the buffer end
#pragma unroll
                for (int i = 0; i < 8; ++i) {
                    int k = k0 + koff + i;
                    v0[i] = (k < D_) ? (_Float16)xr[i] : (_Float16)0.f;
                }
#pragma unroll
                for (int i = 0; i < 8; ++i) {
                    int k = k0 + koff + 8 + i;
                    v1[i] = (k < D_) ? (_Float16)xr[8 + i] : (_Float16)0.f;
                }
            }
            *(half8_t*)&As[srow][koff]     = v0;
            *(half8_t*)&As[srow][koff + 8] = v1;
        }
        // ---- stage B tile: W4T fp16 copy (already transposed + zero-padded) ----
        {
            const _Float16* wr = W4T + (size_t)(n0 + srow) * 224 + (k0 + koff);
            const half8_t* wp = (const half8_t*)wr;
            *(half8_t*)&Bs[srow][koff]     = wp[0];
            *(half8_t*)&Bs[srow][koff + 8] = wp[1];
        }
        __syncthreads();

        // ---- MFMA: A frag A[m=l16][k=quad*8+j], B frag B[k=quad*8+j][n=l16] ----
        half8_t af[4], bf[4];
#pragma unroll
        for (int i = 0; i < 4; ++i) af[i] = *(const half8_t*)&As[mq + i * 16 + l16][quad * 8];
#pragma unroll
        for (int i = 0; i < 4; ++i) bf[i] = *(const half8_t*)&Bs[nq + i * 16 + l16][quad * 8];
#pragma unroll
        for (int mi = 0; mi < 4; ++mi)
#pragma unroll
            for (int ni = 0; ni < 4; ++ni)
                acc[mi][ni] = __builtin_amdgcn_mfma_f32_16x16x32_f16(af[mi], bf[ni], acc[mi][ni], 0, 0, 0);
        __syncthreads();
    }

    // ---- epilogue: C/D layout col = l16, row = quad*4 + r ----
#pragma unroll
    for (int mi = 0; mi < 4; ++mi)
#pragma unroll
        for (int ni = 0; ni < 4; ++ni)
#pragma unroll
            for (int r = 0; r < 4; ++r) {
                int grow = m0 + mq + mi * 16 + quad * 4 + r;
                int gcol = n0 + nq + ni * 16 + l16;
                G[(size_t)grow * 1024 + gcol] = (_Float16)acc[mi][ni][r];
            }
}

// ---------------------------------------------------------------------------
// lstm_rec: one workgroup per batch row, 512 threads (8 waves).
// Thread t owns gate columns n0=t (gates i|f) and n1=t+512 (gates o|z).
// Wh columns register-resident as packed half2 (256 VGPRs/thread).
// h broadcast per step through LDS (fp16), all-fp32 gate math.
// ---------------------------------------------------------------------------
__global__ __launch_bounds__(512, 2) void lstm_rec(
    const _Float16* __restrict__ G,     // [B][S][1024] fp16
    const _Float16* __restrict__ WhT,   // [1024][256] fp16
    const float* __restrict__ bi, const float* __restrict__ bfg,
    const float* __restrict__ bo, const float* __restrict__ bz,
    const float* __restrict__ mask,     // [B][S] fp32
    float* __restrict__ out)            // [B][256] fp32
{
    __shared__ __align__(16) float     pre[1024];
    __shared__ __align__(16) _Float16  hbuf[256];

    const int b  = blockIdx.x;
    const int t  = threadIdx.x;   // 0..511
    const int n1 = t + 512;

    // register-resident Wh columns (packed half2 pairs along k)
    unsigned int wh0[128], wh1[128];
    {
        const unsigned int* p0 = (const unsigned int*)(WhT + (size_t)t  * 256);
        const unsigned int* p1 = (const unsigned int*)(WhT + (size_t)n1 * 256);
#pragma unroll
        for (int k = 0; k < 128; ++k) wh0[k] = p0[k];
#pragma unroll
        for (int k = 0; k < 128; ++k) wh1[k] = p1[k];
    }
    const float bias0 = (t < 256) ? bi[t] : bfg[t - 256];
    const float bias1 = (t < 256) ? bo[t] : bz[t - 256];

    if (t < 256) hbuf[t] = (_Float16)0.f;
    __syncthreads();

    float c = 0.f, acc = 0.f, msum = 0.f;
    const _Float16* Gb = G + (size_t)b * S_ * 1024;
    const float*    mb = mask + (size_t)b * S_;

    for (int s = 0; s < S_; ++s) {
        float a0 = 0.f, a1 = 0.f, a2 = 0.f, a3 = 0.f;
        float d0 = 0.f, d1 = 0.f, d2 = 0.f, d3 = 0.f;
#pragma unroll
        for (int k8 = 0; k8 < 32; ++k8) {
            half8_t hv = *(const half8_t*)(hbuf + k8 * 8);   // ds_read_b128 broadcast
            half2_t h0 = {hv[0], hv[1]};
            half2_t h1 = {hv[2], hv[3]};
            half2_t h2 = {hv[4], hv[5]};
            half2_t h3 = {hv[6], hv[7]};
            a0 = fdot2f(h0, bc_h2(wh0[k8 * 4 + 0]), a0);
            a1 = fdot2f(h1, bc_h2(wh0[k8 * 4 + 1]), a1);
            a2 = fdot2f(h2, bc_h2(wh0[k8 * 4 + 2]), a2);
            a3 = fdot2f(h3, bc_h2(wh0[k8 * 4 + 3]), a3);
            d0 = fdot2f(h0, bc_h2(wh1[k8 * 4 + 0]), d0);
            d1 = fdot2f(h1, bc_h2(wh1[k8 * 4 + 1]), d1);
            d2 = fdot2f(h2, bc_h2(wh1[k8 * 4 + 2]), d2);
            d3 = fdot2f(h3, bc_h2(wh1[k8 * 4 + 3]), d3);
        }
        const float p0 = bias0 + (float)Gb[(size_t)s * 1024 + t]  + ((a0 + a1) + (a2 + a3));
        const float p1 = bias1 + (float)Gb[(size_t)s * 1024 + n1] + ((d0 + d1) + (d2 + d3));
        pre[t]  = p0;
        pre[n1] = p1;
        __syncthreads();
        if (t < 256) {
            // thread t (<256): p0 = gate i preact, p1 = gate o preact (in regs)
            const float fi = fast_sig(p0);
            const float fo = fast_sig(p1);
            const float ff = fast_sig(pre[256 + t]);
            const float fz = fast_tanh(pre[768 + t]);
            c = fi * fz + ff * c;
            const float h = fo * fast_tanh(c);
            const float m = mb[s];
            acc  += m * h;
            msum += m;
            hbuf[t] = (_Float16)h;
        }
        __syncthreads();
    }
    if (t < 256) out[b * 256 + t] = acc / msum;
}

extern "C" void kernel_launch(void* const* d_in, const int* in_sizes, int n_in,
                              void* d_out, int out_size, void* d_ws, size_t ws_size,
                              hipStream_t stream) {
    const float* X    = (const float*)d_in[0];
    const float* mask = (const float*)d_in[1];
    const float* Wi   = (const float*)d_in[2];
    const float* bi   = (const float*)d_in[3];
    const float* Wf   = (const float*)d_in[4];
    const float* bf   = (const float*)d_in[5];
    const float* Wo   = (const float*)d_in[6];
    const float* bo   = (const float*)d_in[7];
    const float* Wz   = (const float*)d_in[8];
    const float* bz   = (const float*)d_in[9];
    float* out = (float*)d_out;

    char* ws = (char*)d_ws;
    _Float16* G   = (_Float16*)ws;                                   // 268,435,456 B
    _Float16* W4T = (_Float16*)(ws + (size_t)B_ * S_ * 1024 * 2);    //     458,752 B
    _Float16* WhT = (_Float16*)(ws + (size_t)B_ * S_ * 1024 * 2 + (size_t)1024 * 224 * 2); // 524,288 B

    hipLaunchKernelGGL(prep,     dim3(1024), dim3(256), 0, stream, Wi, Wf, Wo, Wz, W4T, WhT);
    hipLaunchKernelGGL(gemm_x,   dim3(8192), dim3(256), 0, stream, X, W4T, G);
    hipLaunchKernelGGL(lstm_rec, dim3(B_),   dim3(512), 0, stream, G, WhT, bi, bf, bo, bz, mask, out);
}